// Round 9
// baseline (132.135 us; speedup 1.0000x reference)
//
#include <hip/hip_runtime.h>

#define HQ 32
#define HKV 8
#define DH 128
#define WIN 256
#define META 128
#define QSCALE 0.1275174324f    // rsqrt(128) * log2(e)  (scores produced in log2 space)
#define NFREQ 0.20762050594046f // log2(10000)/64: invfreq(i) = exp2(-NFREQ*i)

typedef __attribute__((ext_vector_type(8))) __bf16 bf16x8;
typedef __attribute__((ext_vector_type(4))) float f32x4;
typedef unsigned short u16;
typedef unsigned int u32;

__device__ __forceinline__ u16 f2bf(float f) {
  u32 u = __float_as_uint(f);
  u += 0x7FFFu + ((u >> 16) & 1u);
  return (u16)(u >> 16);
}
__device__ __forceinline__ u32 packbf(float a, float b) {  // a->lo16, b->hi16
  u32 ua = __float_as_uint(a); ua += 0x7FFFu + ((ua >> 16) & 1u);
  u32 ub = __float_as_uint(b); ub += 0x7FFFu + ((ub >> 16) & 1u);
  return (ua >> 16) | (ub & 0xFFFF0000u);
}

// ---------- prep: RoPE(K) -> Kr[hk][s][d] bf16 ; V -> Vt[hk][d][s] bf16 ----------
__global__ __launch_bounds__(256)
void prep_kv(const float* __restrict__ Kg, const float* __restrict__ Vg,
             u16* __restrict__ Kr, u16* __restrict__ Vt, int S) {
  __shared__ float T[64][132];
  const int hk = blockIdx.x;
  const int s0 = blockIdx.y * 64;
  const int tid = threadIdx.x;
  {
    const int r = tid >> 2, c0 = (tid & 3) * 16;
    const int s = s0 + r;
    const float pos = (float)s;
    const float* src = Kg + ((size_t)s * HKV + hk) * DH;
    u16* dst = Kr + ((size_t)hk * S + s) * DH;
    float x[16], y[16];
    #pragma unroll
    for (int j = 0; j < 16; j += 4) {
      *(float4*)&x[j] = *(const float4*)(src + c0 + j);
      *(float4*)&y[j] = *(const float4*)(src + c0 + 64 + j);
    }
    u16 lo[16], hb[16];
    #pragma unroll
    for (int j = 0; j < 16; ++j) {
      float iv = __builtin_amdgcn_exp2f(-NFREQ * (float)(c0 + j));
      float sv, cv; __sincosf(pos * iv, &sv, &cv);
      lo[j] = f2bf(x[j] * cv - y[j] * sv);
      hb[j] = f2bf(y[j] * cv + x[j] * sv);
    }
    *(int4*)(dst + c0)      = *(int4*)&lo[0];
    *(int4*)(dst + c0 + 8)  = *(int4*)&lo[8];
    *(int4*)(dst + c0 + 64) = *(int4*)&hb[0];
    *(int4*)(dst + c0 + 72) = *(int4*)&hb[8];
  }
  {
    const int r = tid >> 2, c = (tid & 3) * 32;
    const float* src = Vg + ((size_t)(s0 + r) * HKV + hk) * DH + c;
    #pragma unroll
    for (int j = 0; j < 32; j += 4) *(float4*)&T[r][c + j] = *(const float4*)(src + j);
  }
  __syncthreads();
  {
    const int d = tid >> 1, hf = (tid & 1) * 32;
    u16 buf[32];
    #pragma unroll
    for (int i = 0; i < 32; ++i) buf[i] = f2bf(T[hf + i][d]);
    u16* dst = Vt + ((size_t)hk * DH + d) * S + s0 + hf;
    #pragma unroll
    for (int j = 0; j < 4; ++j) *(int4*)(dst + j * 8) = *(int4*)&buf[j * 8];
  }
}

// Register prefetch of next KV tile. NAMED scalars (no arrays/lambdas: R2 alloca trap).
#define LOAD_KV(kv0_) do {                                                 \
    const int4* ks_ = (const int4*)(Kb + (size_t)((kv0_) + kr) * DH + kc); \
    fk0 = ks_[0]; fk1 = ks_[1]; fk2 = ks_[2]; fk3 = ks_[3];                \
    const int4* vs_ = (const int4*)(Vb + (kv0_));                          \
    fv0 = vs_[0]; fv1 = vs_[1]; fv2 = vs_[2]; fv3 = vs_[3];                \
  } while (0)

// Frag-major chunked stores: K row kr cols kc+8p -> KsL[(kr>>4)*4 + (tid&3)]
// lane' = p*16 + (kr&15); V^T row d=tid>>1, kv (tid&1)*32+8p ->
// VsL[(d>>4)*2 + (tid&1)] lane' = p*16 + (d&15). 8 lanes per 4-bank span: balanced.
#define STORE_KV() do {                                                    \
    int4* kd_ = (int4*)&KsL[((kr >> 4) << 2) | (tid & 3)][kr & 15][0];     \
    kd_[0] = fk0; kd_[16] = fk1; kd_[32] = fk2; kd_[48] = fk3;             \
    int4* vd_ = (int4*)&VsL[((tid >> 5) << 1) | (tid & 1)][(tid >> 1) & 15][0]; \
    vd_[0] = fv0; vd_[16] = fv1; vd_[32] = fv2; vd_[48] = fv3;             \
  } while (0)

// ---------- main: flash attention, S^T/O^T, 16 q-rows per wave, 16x16x32 MFMA ----------
// Conflict-free LDS: tiles stored as [chunk][lane][16B] where lane = quad*16+qid is
// exactly the frag-reading lane -> every ds_read_b128 is base + lane*16 (zero conflicts).
// LDS 40960 B x 4 = 160 KiB -> launch_bounds(256,4) targets 4 blocks/CU (16 waves).
__global__ __launch_bounds__(256, 4)
void attn_main(const float* __restrict__ Qg, const u16* __restrict__ Kr,
               const u16* __restrict__ Vt, float* __restrict__ Og, int S) {
  const int h = blockIdx.x;
  const int nqb = gridDim.y;
  const int q0 = (nqb - 1 - blockIdx.y) * 64;   // heavy blocks first
  const int hk = h >> 2;
  const int tid = threadIdx.x;
  const int lane = tid & 63;
  const int wave = tid >> 6;
  const int qid  = lane & 15;      // q col within wave tile (C/D n-index)
  const int quad = lane >> 4;      // 0..3
  const int k8   = quad * 8;       // A/B-frag k offset within a 32-chunk

  // Overlay: prologue Qs[64][136] (17408 B); loop KsL 16384 + VsL 16384 + PsL 8192
  __shared__ __align__(16) char smem[40960];
  u16 (*Qs)[136]      = (u16(*)[136])smem;                  // prologue only
  u16 (*KsL)[64][8]   = (u16(*)[64][8])smem;                // [16][64][8]
  u16 (*VsL)[64][8]   = (u16(*)[64][8])(smem + 16384);      // [16][64][8]
  u16 (*PsL)[2][64][8] = (u16(*)[2][64][8])(smem + 32768);  // [4 waves][2][64][8]

  const u16* Kb = Kr + (size_t)hk * S * DH;
  const u16* Vb = Vt + ((size_t)hk * DH + (tid >> 1)) * S + (tid & 1) * 32;
  const int kr = tid >> 2, kc = (tid & 3) * 32;

  int4 fk0, fk1, fk2, fk3, fv0, fv1, fv2, fv3;
  LOAD_KV(0);   // tile-0 loads fly during the Q prologue

  // ---- prologue: stage Q (64 rows) with RoPE * QSCALE ----
  {
    const int r = tid >> 2, c0 = (tid & 3) * 16;
    const float pos = (float)(q0 + r);
    const float* qrow = Qg + ((size_t)(q0 + r) * HQ + h) * DH;
    float x[16], y[16];
    #pragma unroll
    for (int j = 0; j < 16; j += 4) {
      *(float4*)&x[j] = *(const float4*)(qrow + c0 + j);
      *(float4*)&y[j] = *(const float4*)(qrow + c0 + 64 + j);
    }
    u16 lo[16], hb[16];
    #pragma unroll
    for (int j = 0; j < 16; ++j) {
      float iv = __builtin_amdgcn_exp2f(-NFREQ * (float)(c0 + j));
      float sv, cv; __sincosf(pos * iv, &sv, &cv);
      lo[j] = f2bf((x[j] * cv - y[j] * sv) * QSCALE);
      hb[j] = f2bf((y[j] * cv + x[j] * sv) * QSCALE);
    }
    *(int4*)(&Qs[r][c0])      = *(int4*)&lo[0];
    *(int4*)(&Qs[r][c0 + 8])  = *(int4*)&lo[8];
    *(int4*)(&Qs[r][c0 + 64]) = *(int4*)&hb[0];
    *(int4*)(&Qs[r][c0 + 72]) = *(int4*)&hb[8];
  }
  __syncthreads();
  const int qw0 = q0 + wave * 16;
  const int q   = qw0 + qid;          // this lane's q row
  bf16x8 qa[4];                       // B-frags: Q[q][32c + k8 + j]
  {
    const u16* qb = &Qs[wave * 16 + qid][k8];
    #pragma unroll
    for (int c = 0; c < 4; ++c) qa[c] = *(const bf16x8*)(qb + 32 * c);
  }
  __syncthreads();   // Qs dead; region becomes KsL/VsL
  STORE_KV();        // tile 0 -> LDS
  __syncthreads();

  int wstart = q0 - WIN; if (wstart < META) wstart = META;
  int nwin = (q0 + 64 - wstart) >> 6; if (nwin < 0) nwin = 0;
  const int ntiles = 2 + nwin;        // meta tiles first

  f32x4 acc[8];                       // O^T: acc[D], d = 16D + 4*quad + r, col q
  #pragma unroll
  for (int D = 0; D < 8; ++D)
    #pragma unroll
    for (int r = 0; r < 4; ++r) acc[D][r] = 0.f;
  float m_i = -1e30f, l_i = 0.f;      // l_i is a quad-partial; combined in epilogue

  for (int t = 0; t < ntiles; ++t) {
    const int kv0 = (t < 2) ? t * 64 : wstart + (t - 2) * 64;
    const bool haveNext = (t + 1 < ntiles);
    if (haveNext) {
      const int kvn = (t + 1 < 2) ? (t + 1) * 64 : wstart + (t - 1) * 64;
      LOAD_KV(kvn);
    }

    const bool active = (kv0 <= qw0 + 15) &&
                        ((kv0 < META) || (qw0 - kv0 - 63 <= WIN));
    if (active) {
      // ---- S^T = K Q^T : 4 16x16 C-tiles over kv; frag reads at base+lane*16 ----
      f32x4 sv[4];
      #pragma unroll
      for (int T = 0; T < 4; ++T)
        #pragma unroll
        for (int r = 0; r < 4; ++r) sv[T][r] = 0.f;
      #pragma unroll
      for (int T = 0; T < 4; ++T) {
        #pragma unroll
        for (int c = 0; c < 4; ++c)
          sv[T] = __builtin_amdgcn_mfma_f32_16x16x32_bf16(
                    *(const bf16x8*)&KsL[T * 4 + c][lane][0], qa[c], sv[T], 0, 0, 0);
      }

      // ---- mask (per element: kv = kv0 + 16T + 4*quad + r) ----
      const bool fullv = (kv0 + 63 <= qw0) &&
                         ((kv0 + 63 < META) || (qw0 + 15 - kv0 <= WIN));
      if (!fullv) {
        #pragma unroll
        for (int T = 0; T < 4; ++T) {
          #pragma unroll
          for (int r = 0; r < 4; ++r) {
            const int kv = kv0 + 16 * T + 4 * quad + r;
            if (!((kv <= q) && (((q - kv) <= WIN) || (kv < META)))) sv[T][r] = -1e30f;
          }
        }
      }

      // ---- online softmax: reg reduce + 2 cross-quad shuffles for max ----
      float mx = -1e30f;
      #pragma unroll
      for (int T = 0; T < 4; ++T)
        #pragma unroll
        for (int r = 0; r < 4; ++r) mx = fmaxf(mx, sv[T][r]);
      mx = fmaxf(mx, __shfl_xor(mx, 16));
      mx = fmaxf(mx, __shfl_xor(mx, 32));
      const float mnew = fmaxf(m_i, mx);
      const float al = __builtin_amdgcn_exp2f(m_i - mnew);
      m_i = mnew;
      float ps = 0.f;
      #pragma unroll
      for (int T = 0; T < 4; ++T)
        #pragma unroll
        for (int r = 0; r < 4; ++r) {
          sv[T][r] = __builtin_amdgcn_exp2f(sv[T][r] - mnew);
          ps += sv[T][r];
        }
      l_i = l_i * al + ps;            // quad-partial sum (m shared => consistent)
      #pragma unroll
      for (int D = 0; D < 8; ++D)
        #pragma unroll
        for (int r = 0; r < 4; ++r) acc[D][r] *= al;

      // ---- P: C-layout -> B-layout via wave-private chunked LDS (in-order) ----
      // sv[T][r] is P[q=qid][kv=16T+4quad+r] -> PsL[wave][T>>1]
      //   [lane' = (2*(T&1)+(quad>>1))*16 + qid][j = 4*(quad&1)+r]
      {
        #pragma unroll
        for (int T = 0; T < 4; ++T) {
          u32* pw = (u32*)&PsL[wave][T >> 1]
                      [(((T & 1) << 1) | (quad >> 1)) * 16 + qid][(quad & 1) << 2];
          pw[0] = packbf(sv[T][0], sv[T][1]);
          pw[1] = packbf(sv[T][2], sv[T][3]);
        }
      }
      const bf16x8 p0 = *(const bf16x8*)&PsL[wave][0][lane][0];  // kv 0..31
      const bf16x8 p1 = *(const bf16x8*)&PsL[wave][1][lane][0];  // kv 32..63

      // ---- O^T += V^T P^T : 8 d-tiles x 2 kv-chunks, conflict-free reads ----
      #pragma unroll
      for (int D = 0; D < 8; ++D) {
        acc[D] = __builtin_amdgcn_mfma_f32_16x16x32_bf16(
                   *(const bf16x8*)&VsL[D * 2 + 0][lane][0], p0, acc[D], 0, 0, 0);
        acc[D] = __builtin_amdgcn_mfma_f32_16x16x32_bf16(
                   *(const bf16x8*)&VsL[D * 2 + 1][lane][0], p1, acc[D], 0, 0, 0);
      }
    }

    if (haveNext) {
      __syncthreads();   // all waves done reading KsL/VsL
      STORE_KV();        // prefetched tile -> LDS
      __syncthreads();
    }
  }

  // ---- epilogue: combine quad-partial l, scale, 16B stores ----
  l_i += __shfl_xor(l_i, 16);
  l_i += __shfl_xor(l_i, 32);
  const float inv = 1.0f / l_i;
  float* ob = Og + ((size_t)q * HQ + h) * DH;
  #pragma unroll
  for (int D = 0; D < 8; ++D) {       // d = 16D + 4*quad + {0..3}
    float4 o = { acc[D][0] * inv, acc[D][1] * inv, acc[D][2] * inv, acc[D][3] * inv };
    *(float4*)(ob + 16 * D + 4 * quad) = o;
  }
}

extern "C" void kernel_launch(void* const* d_in, const int* in_sizes, int n_in,
                              void* d_out, int out_size, void* d_ws, size_t ws_size,
                              hipStream_t stream) {
  const float* Qg = (const float*)d_in[0];
  const float* Kg = (const float*)d_in[1];
  const float* Vg = (const float*)d_in[2];
  float* Og = (float*)d_out;
  const int S = in_sizes[0] / (HQ * DH);   // 2176

  u16* Kr = (u16*)d_ws;                                     // 4.45 MB
  u16* Vt = (u16*)((char*)d_ws + (size_t)HKV * S * DH * 2); // 4.45 MB

  prep_kv<<<dim3(HKV, S / 64), dim3(256), 0, stream>>>(Kg, Vg, Kr, Vt, S);
  attn_main<<<dim3(HQ, S / 64), dim3(256), 0, stream>>>(Qg, Kr, Vt, Og, S);
}